// Round 2
// baseline (219.831 us; speedup 1.0000x reference)
//
#include <hip/hip_runtime.h>
#include <hip/hip_bf16.h>

// FenwickLogLinearAttention: B=2,T=2048,C=1024,H=16,Dh=64
// R5 = MEASUREMENT PROBE. Identical kernels to R4; kernel_launch runs the whole
//     4-kernel pipeline TWICE (idempotent -> bit-identical output). The dur_us
//     delta vs R4 (149.15) equals the true summed duration of my kernels,
//     separating kernel time from harness-fixed time (timed 268MB poison fills
//     vs per-launch overhead vs slow kernels). Revert to single pipeline next round.
// ws layout (bytes): xb@0 (8M) | WqkvT@8M (6M) | QKVb@14M (24M) | AO@38M (8M) | WprojT@46M (2M)

typedef unsigned short ushort_t;
typedef __attribute__((ext_vector_type(8))) short s16x8;
typedef __attribute__((ext_vector_type(4))) float f32x4;

#define T_SEQ 2048
#define C_DIM 1024
#define HEADS 16

__device__ __forceinline__ ushort_t f2bf(float f) {
    union { float f; unsigned u; } v{f};
    unsigned r = v.u + 0x7FFFu + ((v.u >> 16) & 1u);   // RNE
    return (ushort_t)(r >> 16);
}
__device__ __forceinline__ float bf2f(ushort_t u) {
    union { unsigned u; float f; } v{((unsigned)u) << 16};
    return v.f;
}

__device__ __forceinline__ void async16(const ushort_t* g, ushort_t* l) {
    __builtin_amdgcn_global_load_lds(
        (const __attribute__((address_space(1))) void*)g,
        (__attribute__((address_space(3))) void*)l, 16, 0, 0);
}

// ---------------- merged prep: cvt(x)->bf16 + two weight transposes ----------------
__global__ void prep(const float* __restrict__ x, ushort_t* __restrict__ xb,
                     const float* __restrict__ Wq, ushort_t* __restrict__ WqT,
                     const float* __restrict__ Wp, ushort_t* __restrict__ WpT) {
    const int bid = blockIdx.x;
    const int tid = threadIdx.x;
    if (bid < 4096) {
        const int i = bid * 256 + tid;
        float4 f = ((const float4*)x)[i];
        ushort4 o;
        o.x = f2bf(f.x); o.y = f2bf(f.y); o.z = f2bf(f.z); o.w = f2bf(f.w);
        ((ushort4*)xb)[i] = o;
    } else {
        __shared__ ushort_t tile[32][33];
        const float* W; ushort_t* WT; int N, nb, kb;
        if (bid < 7168) {
            const int tb = bid - 4096;
            W = Wq; WT = WqT; N = 3072; nb = (tb % 96) * 32; kb = (tb / 96) * 32;
        } else {
            const int tb = bid - 7168;
            W = Wp; WT = WpT; N = 1024; nb = (tb & 31) * 32; kb = (tb >> 5) * 32;
        }
        const int tx = tid & 31, ty = tid >> 5;
        #pragma unroll
        for (int i = ty; i < 32; i += 8)
            tile[i][tx] = f2bf(W[(size_t)(kb + i) * N + nb + tx]);
        __syncthreads();
        #pragma unroll
        for (int i = ty; i < 32; i += 8)
            WT[(size_t)(nb + i) * 1024 + kb + tx] = tile[tx][i];
    }
}

// ---------------- QKV GEMM: 256x192 tile, BK=64, 8-phase counted-vmcnt ----------------
#define BAR()  do { __builtin_amdgcn_sched_barrier(0); __builtin_amdgcn_s_barrier(); \
                    __builtin_amdgcn_sched_barrier(0); } while (0)
#define WAIT_LGKM0() do { asm volatile("s_waitcnt lgkmcnt(0)" ::: "memory"); \
                          __builtin_amdgcn_sched_barrier(0); } while (0)
#define WAIT_VM(n)  asm volatile("s_waitcnt vmcnt(" #n ")" ::: "memory")

#define SA(kt, u, dst) async16(Ag + (size_t)(u) * rstep + (size_t)(kt) * 64, \
                               (dst) + (u) * 4096 + wave * 512)
#define SB(kt, u, dst) async16(Bg + (size_t)(u) * rstep + (size_t)(kt) * 64, \
                               (dst) + (u) * 4096 + wave * 512)

#define LDA_FRAG(buf, i, kh) (*(const s16x8*)((buf) + ((wm << 7) + (i) * 16 + lrow) * 64 \
                               + ((((kh) * 4 + quad) ^ d3) << 3)))
#define LDB_FRAG(buf, j, kh) (*(const s16x8*)((buf) + (wn * 48 + (j) * 16 + lrow) * 64 \
                               + ((((kh) * 4 + quad) ^ d3) << 3)))

#define PHASE(lAb, lBb, Q, LOADB, STAGES, ENDWAIT)                              \
  {                                                                             \
    s16x8 af[2][2];                                                             \
    _Pragma("unroll") for (int ii = 0; ii < 2; ++ii)                            \
      _Pragma("unroll") for (int kh = 0; kh < 2; ++kh)                          \
        af[ii][kh] = LDA_FRAG(lAb, 2 * (Q) + ii, kh);                           \
    if (LOADB) {                                                                \
      _Pragma("unroll") for (int j = 0; j < 3; ++j)                             \
        _Pragma("unroll") for (int kh = 0; kh < 2; ++kh)                        \
          bf[j][kh] = LDB_FRAG(lBb, j, kh);                                     \
    }                                                                           \
    STAGES;                                                                     \
    BAR();                                                                      \
    WAIT_LGKM0();                                                               \
    __builtin_amdgcn_s_setprio(1);                                              \
    _Pragma("unroll") for (int ii = 0; ii < 2; ++ii)                            \
      _Pragma("unroll") for (int j = 0; j < 3; ++j)                             \
        _Pragma("unroll") for (int kh = 0; kh < 2; ++kh)                        \
          acc[2 * (Q) + ii][j] = __builtin_amdgcn_mfma_f32_16x16x32_bf16(       \
              af[ii][kh], bf[j][kh], acc[2 * (Q) + ii][j], 0, 0, 0);            \
    __builtin_amdgcn_s_setprio(0);                                              \
    ENDWAIT;                                                                    \
    BAR();                                                                      \
  }

__global__ __launch_bounds__(512, 2)
void gemm_qkv(const ushort_t* __restrict__ A, const ushort_t* __restrict__ BT,
              const float* __restrict__ bias, ushort_t* __restrict__ C,
              int N, int K) {
    __shared__ ushort_t lds[57344];          // 112 KiB

    const int tid  = threadIdx.x;
    const int wave = tid >> 6;
    const int lane = tid & 63;
    const int wm   = wave >> 2;              // 0..1  (M half)
    const int wn   = wave & 3;               // 0..3  (N quarter: 48 cols)
    const int lrow = lane & 15;
    const int quad = lane >> 4;
    const int d3   = lrow & 7;
    const int crow = lane >> 3;
    const int gcol = (((lane & 7) ^ crow) << 3);   // pre-swizzled global k-group
    const int row0 = blockIdx.x * 256;
    const int col0 = blockIdx.y * 192;

    ushort_t* const lA0 = lds;                       // A buf0: 16384 el
    ushort_t* const lB0 = lds + 16384;               // B buf0: 12288 el
    ushort_t* const lA1 = lds + 28672;               // A buf1
    ushort_t* const lB1 = lds + 45056;               // B buf1

    const ushort_t* Ag = A  + (size_t)(row0 + wave * 8 + crow) * K + gcol;
    const ushort_t* Bg = BT + (size_t)(col0 + wave * 8 + crow) * K + gcol;
    const size_t rstep = (size_t)64 * K;             // 64-row stage unit

    f32x4 acc[8][3] = {};
    s16x8 bf[3][2];

    // prologue: tile0 fully (7 loads), tile1 partial (5) -> vmcnt(5)
    SA(0, 0, lA0); SA(0, 1, lA0); SA(0, 2, lA0); SA(0, 3, lA0);
    SB(0, 0, lB0); SB(0, 1, lB0); SB(0, 2, lB0);
    SB(1, 0, lB1); SB(1, 1, lB1); SA(1, 0, lA1); SA(1, 2, lA1); SB(1, 2, lB1);
    WAIT_VM(5);
    BAR();

    const int nt = K >> 6;                           // 16 K-tiles
    for (int t = 0; t < nt; t += 2) {
        const bool s2 = (t + 2) < nt;
        const bool s3 = (t + 3) < nt;
        PHASE(lA0, lB0, 0, true,  { SA(t + 1, 1, lA1); SA(t + 1, 3, lA1); }, {});
        PHASE(lA0, lB0, 1, false, { if (s2) { SB(t + 2, 0, lB0); SB(t + 2, 1, lB0); } }, {});
        PHASE(lA0, lB0, 2, false, { if (s2) { SA(t + 2, 0, lA0); SA(t + 2, 2, lA0); } }, {});
        PHASE(lA0, lB0, 3, false, { if (s2) { SB(t + 2, 2, lB0); } },
              { if (s2) { WAIT_VM(5); } else { WAIT_VM(0); } });
        PHASE(lA1, lB1, 0, true,  { if (s2) { SA(t + 2, 1, lA0); SA(t + 2, 3, lA0); } }, {});
        PHASE(lA1, lB1, 1, false, { if (s3) { SB(t + 3, 0, lB1); SB(t + 3, 1, lB1); } }, {});
        PHASE(lA1, lB1, 2, false, { if (s3) { SA(t + 3, 0, lA1); SA(t + 3, 2, lA1); } }, {});
        PHASE(lA1, lB1, 3, false, { if (s3) { SB(t + 3, 2, lB1); } },
              { WAIT_VM(5); });
    }

    // D mapping: col=lane&15, row=quad*4+reg (m89-verified)
    #pragma unroll
    for (int i = 0; i < 8; ++i) {
        #pragma unroll
        for (int j = 0; j < 3; ++j) {
            const int col = col0 + wn * 48 + j * 16 + lrow;
            const float bv = bias[col];
            #pragma unroll
            for (int r = 0; r < 4; ++r) {
                const int row = row0 + (wm << 7) + i * 16 + quad * 4 + r;
                C[(size_t)row * N + col] = f2bf(acc[i][j][r] + bv);
            }
        }
    }
}

// ---------------- proj GEMM: 128x64 tile, BK=64, swizzled LDS, fp32 out ----------------
__global__ void gemm_proj(const ushort_t* __restrict__ A, const ushort_t* __restrict__ BT,
                          const float* __restrict__ bias, float* __restrict__ C,
                          int N, int K) {
    __shared__ ushort_t lsA[128 * 64];
    __shared__ ushort_t lsB[64 * 64];

    const int tid  = threadIdx.x;
    const int wave = tid >> 6;
    const int lane = tid & 63;
    const int row0 = blockIdx.x * 128;
    const int col0 = blockIdx.y * 64;
    const int lrow = lane & 15;
    const int quad = lane >> 4;
    const int crow = lane >> 3;
    const int gcol = ((lane & 7) ^ crow) * 8;
    const int d3   = lrow & 7;

    f32x4 acc[2][4] = {};

    for (int k0 = 0; k0 < K; k0 += 64) {
        #pragma unroll
        for (int it = 0; it < 4; ++it) {
            const int chunk = it * 4 + wave;           // A: 16 chunks
            const int r = chunk * 8 + crow;
            async16(A + (size_t)(row0 + r) * K + (k0 + gcol), lsA + chunk * 512);
        }
        #pragma unroll
        for (int it = 0; it < 2; ++it) {
            const int chunk = it * 4 + wave;           // B: 8 chunks
            const int r = chunk * 8 + crow;
            async16(BT + (size_t)(col0 + r) * K + (k0 + gcol), lsB + chunk * 512);
        }
        __syncthreads();
        #pragma unroll
        for (int kk = 0; kk < 64; kk += 32) {
            const int g = (kk >> 3) + quad;
            const int slot = (g ^ d3) << 3;
            s16x8 af[2], bfr[4];
            #pragma unroll
            for (int i = 0; i < 2; ++i)
                af[i] = *(const s16x8*)(lsA + (wave * 32 + i * 16 + lrow) * 64 + slot);
            #pragma unroll
            for (int j = 0; j < 4; ++j)
                bfr[j] = *(const s16x8*)(lsB + (j * 16 + lrow) * 64 + slot);
            #pragma unroll
            for (int i = 0; i < 2; ++i)
                #pragma unroll
                for (int j = 0; j < 4; ++j)
                    acc[i][j] = __builtin_amdgcn_mfma_f32_16x16x32_bf16(
                        af[i], bfr[j], acc[i][j], 0, 0, 0);
        }
        __syncthreads();
    }

    #pragma unroll
    for (int i = 0; i < 2; ++i) {
        #pragma unroll
        for (int j = 0; j < 4; ++j) {
            const int col = col0 + j * 16 + lrow;
            const float bv = bias[col];
            #pragma unroll
            for (int r = 0; r < 4; ++r) {
                const int row = row0 + wave * 32 + i * 16 + quad * 4 + r;
                C[(size_t)row * N + col] = acc[i][j][r] + bv;
            }
        }
    }
}

// ---------------- sparse Fenwick attention ----------------
__global__ void fenwick_attn(const ushort_t* __restrict__ QKV, ushort_t* __restrict__ AO) {
    const int lane = threadIdx.x & 63;
    const int wid  = blockIdx.x * 4 + (threadIdx.x >> 6);
    const int tile = wid & 255;
    const int bh   = wid >> 8;
    const int h    = bh & (HEADS - 1);
    const int b    = bh >> 4;
    const int tl   = lane >> 3;
    const int g    = lane & 7;
    const int t    = tile * 8 + tl;

    const ushort_t* base = QKV + (size_t)(b * T_SEQ) * 3072 + h * 64 + g * 8;

    float qf[8];
    {
        s16x8 qv = *(const s16x8*)(base + (size_t)t * 3072);
        #pragma unroll
        for (int e = 0; e < 8; ++e) qf[e] = bf2f((ushort_t)qv[e]);
    }

    float logit[12];
    int   pos[12];
    float mx = -1e30f;
    #pragma unroll
    for (int s = 0; s < 12; ++s) {
        const int step = (s == 0) ? 0 : (1 << (s - 1));
        const bool act = (step <= t);
        const int p = act ? (t - step) : t;
        pos[s] = p;
        s16x8 kv = *(const s16x8*)(base + (size_t)p * 3072 + 1024);
        float l = 0.f;
        #pragma unroll
        for (int e = 0; e < 8; ++e) l = fmaf(qf[e], bf2f((ushort_t)kv[e]), l);
        l += __shfl_xor(l, 1, 64);
        l += __shfl_xor(l, 2, 64);
        l += __shfl_xor(l, 4, 64);
        l *= 0.125f;                       // Dh^-0.5
        logit[s] = act ? l : -1e30f;
        mx = fmaxf(mx, logit[s]);
    }

    float denom = 0.f;
    float ov[8] = {};
    #pragma unroll
    for (int s = 0; s < 12; ++s) {
        const float w = __expf(logit[s] - mx);
        denom += w;
        s16x8 vv = *(const s16x8*)(base + (size_t)pos[s] * 3072 + 2048);
        #pragma unroll
        for (int e = 0; e < 8; ++e) ov[e] = fmaf(w, bf2f((ushort_t)vv[e]), ov[e]);
    }

    const float inv = 1.f / denom;
    s16x8 os;
    #pragma unroll
    for (int e = 0; e < 8; ++e) os[e] = (short)f2bf(ov[e] * inv);
    *(s16x8*)(AO + (size_t)(b * T_SEQ + t) * C_DIM + h * 64 + g * 8) = os;
}

extern "C" void kernel_launch(void* const* d_in, const int* in_sizes, int n_in,
                              void* d_out, int out_size, void* d_ws, size_t ws_size,
                              hipStream_t stream) {
    const float* x      = (const float*)d_in[0];
    const float* W_qkv  = (const float*)d_in[1];
    const float* b_qkv  = (const float*)d_in[2];
    const float* W_proj = (const float*)d_in[3];
    const float* b_proj = (const float*)d_in[4];
    float* out = (float*)d_out;

    char* ws = (char*)d_ws;
    ushort_t* xb     = (ushort_t*)(ws);                        // 4096x1024 bf16
    ushort_t* WqkvT  = (ushort_t*)(ws + (size_t)8  * 1048576); // 3072x1024 bf16
    ushort_t* QKVb   = (ushort_t*)(ws + (size_t)14 * 1048576); // 4096x3072 bf16
    ushort_t* AO     = (ushort_t*)(ws + (size_t)38 * 1048576); // 4096x1024 bf16
    ushort_t* WprojT = (ushort_t*)(ws + (size_t)46 * 1048576); // 1024x1024 bf16

    // PROBE: run the full (idempotent) pipeline twice; Δdur vs R4 = Σ kernel time.
    for (int rep = 0; rep < 2; ++rep) {
        prep<<<8192, 256, 0, stream>>>(x, xb, W_qkv, WqkvT, W_proj, WprojT);
        gemm_qkv<<<dim3(16, 16), 512, 0, stream>>>(xb, WqkvT, b_qkv, QKVb, 3072, 1024);
        fenwick_attn<<<2048, 256, 0, stream>>>(QKVb, AO);
        gemm_proj<<<dim3(32, 16), 256, 0, stream>>>(AO, WprojT, b_proj, out, 1024, 1024);
    }
}

// Round 3
// 148.102 us; speedup vs baseline: 1.4843x; 1.4843x over previous
//
#include <hip/hip_runtime.h>
#include <hip/hip_bf16.h>

// FenwickLogLinearAttention: B=2,T=2048,C=1024,H=16,Dh=64
// R6: L2-residency round (probe R5 showed kernels=70.7us, fixed harness=78.4us;
//     qkv/attn/proj are all L3-BW-bound on re-read traffic, not schedule-bound).
//  - gemm_qkv: 8-phase kept; grid 1D-256 with XCD 4x8 region swizzle
//    (per-XCD working set A 2MB + B 3MB -> L2-resident staging).
//  - fenwick_attn: bh-per-XCD swizzle (each XCD serves 4 bh's, 2MB K/V set).
//  - gemm_proj: retiled 128x128 (R3 2-barrier structure), 256 blocks=1/CU,
//    XCD owns 4 rowblks x all cols (3.1MB set); HBM traffic ~42MB.
// ws layout (bytes): xb@0 (8M) | WqkvT@8M (6M) | QKVb@14M (24M) | AO@38M (8M) | WprojT@46M (2M)

typedef unsigned short ushort_t;
typedef __attribute__((ext_vector_type(8))) short s16x8;
typedef __attribute__((ext_vector_type(4))) float f32x4;

#define T_SEQ 2048
#define C_DIM 1024
#define HEADS 16

__device__ __forceinline__ ushort_t f2bf(float f) {
    union { float f; unsigned u; } v{f};
    unsigned r = v.u + 0x7FFFu + ((v.u >> 16) & 1u);   // RNE
    return (ushort_t)(r >> 16);
}
__device__ __forceinline__ float bf2f(ushort_t u) {
    union { unsigned u; float f; } v{((unsigned)u) << 16};
    return v.f;
}

__device__ __forceinline__ void async16(const ushort_t* g, ushort_t* l) {
    __builtin_amdgcn_global_load_lds(
        (const __attribute__((address_space(1))) void*)g,
        (__attribute__((address_space(3))) void*)l, 16, 0, 0);
}

// ---------------- merged prep: cvt(x)->bf16 + two weight transposes ----------------
__global__ void prep(const float* __restrict__ x, ushort_t* __restrict__ xb,
                     const float* __restrict__ Wq, ushort_t* __restrict__ WqT,
                     const float* __restrict__ Wp, ushort_t* __restrict__ WpT) {
    const int bid = blockIdx.x;
    const int tid = threadIdx.x;
    if (bid < 4096) {
        const int i = bid * 256 + tid;
        float4 f = ((const float4*)x)[i];
        ushort4 o;
        o.x = f2bf(f.x); o.y = f2bf(f.y); o.z = f2bf(f.z); o.w = f2bf(f.w);
        ((ushort4*)xb)[i] = o;
    } else {
        __shared__ ushort_t tile[32][33];
        const float* W; ushort_t* WT; int N, nb, kb;
        if (bid < 7168) {
            const int tb = bid - 4096;
            W = Wq; WT = WqT; N = 3072; nb = (tb % 96) * 32; kb = (tb / 96) * 32;
        } else {
            const int tb = bid - 7168;
            W = Wp; WT = WpT; N = 1024; nb = (tb & 31) * 32; kb = (tb >> 5) * 32;
        }
        const int tx = tid & 31, ty = tid >> 5;
        #pragma unroll
        for (int i = ty; i < 32; i += 8)
            tile[i][tx] = f2bf(W[(size_t)(kb + i) * N + nb + tx]);
        __syncthreads();
        #pragma unroll
        for (int i = ty; i < 32; i += 8)
            WT[(size_t)(nb + i) * 1024 + kb + tx] = tile[tx][i];
    }
}

// ---------------- QKV GEMM: 256x192 tile, BK=64, 8-phase counted-vmcnt ----------------
#define BAR()  do { __builtin_amdgcn_sched_barrier(0); __builtin_amdgcn_s_barrier(); \
                    __builtin_amdgcn_sched_barrier(0); } while (0)
#define WAIT_LGKM0() do { asm volatile("s_waitcnt lgkmcnt(0)" ::: "memory"); \
                          __builtin_amdgcn_sched_barrier(0); } while (0)
#define WAIT_VM(n)  asm volatile("s_waitcnt vmcnt(" #n ")" ::: "memory")

#define SA(kt, u, dst) async16(Ag + (size_t)(u) * rstep + (size_t)(kt) * 64, \
                               (dst) + (u) * 4096 + wave * 512)
#define SB(kt, u, dst) async16(Bg + (size_t)(u) * rstep + (size_t)(kt) * 64, \
                               (dst) + (u) * 4096 + wave * 512)

#define LDA_FRAG(buf, i, kh) (*(const s16x8*)((buf) + ((wm << 7) + (i) * 16 + lrow) * 64 \
                               + ((((kh) * 4 + quad) ^ d3) << 3)))
#define LDB_FRAG(buf, j, kh) (*(const s16x8*)((buf) + (wn * 48 + (j) * 16 + lrow) * 64 \
                               + ((((kh) * 4 + quad) ^ d3) << 3)))

#define PHASE(lAb, lBb, Q, LOADB, STAGES, ENDWAIT)                              \
  {                                                                             \
    s16x8 af[2][2];                                                             \
    _Pragma("unroll") for (int ii = 0; ii < 2; ++ii)                            \
      _Pragma("unroll") for (int kh = 0; kh < 2; ++kh)                          \
        af[ii][kh] = LDA_FRAG(lAb, 2 * (Q) + ii, kh);                           \
    if (LOADB) {                                                                \
      _Pragma("unroll") for (int j = 0; j < 3; ++j)                             \
        _Pragma("unroll") for (int kh = 0; kh < 2; ++kh)                        \
          bf[j][kh] = LDB_FRAG(lBb, j, kh);                                     \
    }                                                                           \
    STAGES;                                                                     \
    BAR();                                                                      \
    WAIT_LGKM0();                                                               \
    __builtin_amdgcn_s_setprio(1);                                              \
    _Pragma("unroll") for (int ii = 0; ii < 2; ++ii)                            \
      _Pragma("unroll") for (int j = 0; j < 3; ++j)                             \
        _Pragma("unroll") for (int kh = 0; kh < 2; ++kh)                        \
          acc[2 * (Q) + ii][j] = __builtin_amdgcn_mfma_f32_16x16x32_bf16(       \
              af[ii][kh], bf[j][kh], acc[2 * (Q) + ii][j], 0, 0, 0);            \
    __builtin_amdgcn_s_setprio(0);                                              \
    ENDWAIT;                                                                    \
    BAR();                                                                      \
  }

__global__ __launch_bounds__(512, 2)
void gemm_qkv(const ushort_t* __restrict__ A, const ushort_t* __restrict__ BT,
              const float* __restrict__ bias, ushort_t* __restrict__ C,
              int N, int K) {
    __shared__ ushort_t lds[57344];          // 112 KiB

    const int tid  = threadIdx.x;
    const int wave = tid >> 6;
    const int lane = tid & 63;
    const int wm   = wave >> 2;              // 0..1  (M half)
    const int wn   = wave & 3;               // 0..3  (N quarter: 48 cols)
    const int lrow = lane & 15;
    const int quad = lane >> 4;
    const int d3   = lrow & 7;
    const int crow = lane >> 3;
    const int gcol = (((lane & 7) ^ crow) << 3);   // pre-swizzled global k-group

    // XCD region swizzle: XCD (bid&7) owns a 4-rowblk x 8-colblk region.
    // Working set: A 4x512KB + B 8x384KB = 5MB, mostly L2-resident per XCD.
    const int bid    = blockIdx.x;
    const int xcd    = bid & 7;
    const int q      = bid >> 3;                   // [0,32)
    const int rowblk = ((xcd & 3) << 2) + (q & 3); // [0,16)
    const int colblk = ((xcd >> 2) << 3) + (q >> 2);// [0,16)
    const int row0   = rowblk * 256;
    const int col0   = colblk * 192;

    ushort_t* const lA0 = lds;                       // A buf0: 16384 el
    ushort_t* const lB0 = lds + 16384;               // B buf0: 12288 el
    ushort_t* const lA1 = lds + 28672;               // A buf1
    ushort_t* const lB1 = lds + 45056;               // B buf1

    const ushort_t* Ag = A  + (size_t)(row0 + wave * 8 + crow) * K + gcol;
    const ushort_t* Bg = BT + (size_t)(col0 + wave * 8 + crow) * K + gcol;
    const size_t rstep = (size_t)64 * K;             // 64-row stage unit

    f32x4 acc[8][3] = {};
    s16x8 bf[3][2];

    // prologue: tile0 fully (7 loads), tile1 partial (5) -> vmcnt(5)
    SA(0, 0, lA0); SA(0, 1, lA0); SA(0, 2, lA0); SA(0, 3, lA0);
    SB(0, 0, lB0); SB(0, 1, lB0); SB(0, 2, lB0);
    SB(1, 0, lB1); SB(1, 1, lB1); SA(1, 0, lA1); SA(1, 2, lA1); SB(1, 2, lB1);
    WAIT_VM(5);
    BAR();

    const int nt = K >> 6;                           // 16 K-tiles
    for (int t = 0; t < nt; t += 2) {
        const bool s2 = (t + 2) < nt;
        const bool s3 = (t + 3) < nt;
        PHASE(lA0, lB0, 0, true,  { SA(t + 1, 1, lA1); SA(t + 1, 3, lA1); }, {});
        PHASE(lA0, lB0, 1, false, { if (s2) { SB(t + 2, 0, lB0); SB(t + 2, 1, lB0); } }, {});
        PHASE(lA0, lB0, 2, false, { if (s2) { SA(t + 2, 0, lA0); SA(t + 2, 2, lA0); } }, {});
        PHASE(lA0, lB0, 3, false, { if (s2) { SB(t + 2, 2, lB0); } },
              { if (s2) { WAIT_VM(5); } else { WAIT_VM(0); } });
        PHASE(lA1, lB1, 0, true,  { if (s2) { SA(t + 2, 1, lA0); SA(t + 2, 3, lA0); } }, {});
        PHASE(lA1, lB1, 1, false, { if (s3) { SB(t + 3, 0, lB1); SB(t + 3, 1, lB1); } }, {});
        PHASE(lA1, lB1, 2, false, { if (s3) { SA(t + 3, 0, lA1); SA(t + 3, 2, lA1); } }, {});
        PHASE(lA1, lB1, 3, false, { if (s3) { SB(t + 3, 2, lB1); } },
              { WAIT_VM(5); });
    }

    // D mapping: col=lane&15, row=quad*4+reg (m89-verified)
    #pragma unroll
    for (int i = 0; i < 8; ++i) {
        #pragma unroll
        for (int j = 0; j < 3; ++j) {
            const int col = col0 + wn * 48 + j * 16 + lrow;
            const float bv = bias[col];
            #pragma unroll
            for (int r = 0; r < 4; ++r) {
                const int row = row0 + (wm << 7) + i * 16 + quad * 4 + r;
                C[(size_t)row * N + col] = f2bf(acc[i][j][r] + bv);
            }
        }
    }
}

// ---------------- proj GEMM: 128x128 tile, BK=64, swizzled LDS, fp32 out ----------------
// 256 blocks = 1/CU; XCD (bid&7) owns rowblks [4*xcd, 4*xcd+4) x all 8 colblks:
// per-XCD working set A 1MB + B 2.1MB = 3.1MB < 4MB L2 -> re-reads are L2 hits.
__global__ void gemm_proj(const ushort_t* __restrict__ A, const ushort_t* __restrict__ BT,
                          const float* __restrict__ bias, float* __restrict__ C,
                          int N, int K) {
    __shared__ ushort_t lsA[128 * 64];
    __shared__ ushort_t lsB[128 * 64];

    const int tid  = threadIdx.x;
    const int wave = tid >> 6;
    const int lane = tid & 63;

    const int bid  = blockIdx.x;
    const int xcd  = bid & 7;
    const int q    = bid >> 3;                 // [0,32)
    const int row0 = (xcd * 4 + (q & 3)) * 128;   // rowblk [0,32)
    const int col0 = (q >> 2) * 128;              // colblk [0,8)

    const int wr   = (wave >> 1) * 64;
    const int wc   = (wave & 1) * 64;
    const int lrow = lane & 15;
    const int quad = lane >> 4;
    const int crow = lane >> 3;
    const int gcol = ((lane & 7) ^ crow) * 8;
    const int d3   = lrow & 7;

    f32x4 acc[4][4] = {};

    for (int k0 = 0; k0 < K; k0 += 64) {
        #pragma unroll
        for (int it = 0; it < 4; ++it) {
            const int chunk = it * 4 + wave;           // 16 chunks x 1KB each
            const int r = chunk * 8 + crow;
            async16(A  + (size_t)(row0 + r) * K + (k0 + gcol), lsA + chunk * 512);
            async16(BT + (size_t)(col0 + r) * K + (k0 + gcol), lsB + chunk * 512);
        }
        __syncthreads();   // drains vmcnt -> staged data visible
        #pragma unroll
        for (int kk = 0; kk < 64; kk += 32) {
            const int g = (kk >> 3) + quad;
            const int slot = (g ^ d3) << 3;
            s16x8 af[4], bfr[4];
            #pragma unroll
            for (int i = 0; i < 4; ++i)
                af[i] = *(const s16x8*)(lsA + (wr + i * 16 + lrow) * 64 + slot);
            #pragma unroll
            for (int j = 0; j < 4; ++j)
                bfr[j] = *(const s16x8*)(lsB + (wc + j * 16 + lrow) * 64 + slot);
            #pragma unroll
            for (int i = 0; i < 4; ++i)
                #pragma unroll
                for (int j = 0; j < 4; ++j)
                    acc[i][j] = __builtin_amdgcn_mfma_f32_16x16x32_bf16(
                        af[i], bfr[j], acc[i][j], 0, 0, 0);
        }
        __syncthreads();
    }

    #pragma unroll
    for (int i = 0; i < 4; ++i) {
        #pragma unroll
        for (int j = 0; j < 4; ++j) {
            const int col = col0 + wc + j * 16 + lrow;
            const float bv = bias[col];
            #pragma unroll
            for (int r = 0; r < 4; ++r) {
                const int row = row0 + wr + i * 16 + quad * 4 + r;
                C[(size_t)row * N + col] = acc[i][j][r] + bv;
            }
        }
    }
}

// ---------------- sparse Fenwick attention ----------------
// bh-per-XCD swizzle: XCD x serves bh in {x, x+8, x+16, x+24} (64 blocks each);
// per-XCD K/V working set = 4 x 512KB = 2MB < 4MB L2.
__global__ void fenwick_attn(const ushort_t* __restrict__ QKV, ushort_t* __restrict__ AO) {
    const int lane = threadIdx.x & 63;
    const int bid  = blockIdx.x;
    const int xcd  = bid & 7;
    const int q    = bid >> 3;                       // [0,256)
    const int bh   = xcd + ((q >> 6) << 3);          // [0,32)
    const int tile = ((q & 63) << 2) + (threadIdx.x >> 6); // [0,256)
    const int h    = bh & (HEADS - 1);
    const int b    = bh >> 4;
    const int tl   = lane >> 3;
    const int g    = lane & 7;
    const int t    = tile * 8 + tl;

    const ushort_t* base = QKV + (size_t)(b * T_SEQ) * 3072 + h * 64 + g * 8;

    float qf[8];
    {
        s16x8 qv = *(const s16x8*)(base + (size_t)t * 3072);
        #pragma unroll
        for (int e = 0; e < 8; ++e) qf[e] = bf2f((ushort_t)qv[e]);
    }

    float logit[12];
    int   pos[12];
    float mx = -1e30f;
    #pragma unroll
    for (int s = 0; s < 12; ++s) {
        const int step = (s == 0) ? 0 : (1 << (s - 1));
        const bool act = (step <= t);
        const int p = act ? (t - step) : t;
        pos[s] = p;
        s16x8 kv = *(const s16x8*)(base + (size_t)p * 3072 + 1024);
        float l = 0.f;
        #pragma unroll
        for (int e = 0; e < 8; ++e) l = fmaf(qf[e], bf2f((ushort_t)kv[e]), l);
        l += __shfl_xor(l, 1, 64);
        l += __shfl_xor(l, 2, 64);
        l += __shfl_xor(l, 4, 64);
        l *= 0.125f;                       // Dh^-0.5
        logit[s] = act ? l : -1e30f;
        mx = fmaxf(mx, logit[s]);
    }

    float denom = 0.f;
    float ov[8] = {};
    #pragma unroll
    for (int s = 0; s < 12; ++s) {
        const float w = __expf(logit[s] - mx);
        denom += w;
        s16x8 vv = *(const s16x8*)(base + (size_t)pos[s] * 3072 + 2048);
        #pragma unroll
        for (int e = 0; e < 8; ++e) ov[e] = fmaf(w, bf2f((ushort_t)vv[e]), ov[e]);
    }

    const float inv = 1.f / denom;
    s16x8 os;
    #pragma unroll
    for (int e = 0; e < 8; ++e) os[e] = (short)f2bf(ov[e] * inv);
    *(s16x8*)(AO + (size_t)(b * T_SEQ + t) * C_DIM + h * 64 + g * 8) = os;
}

extern "C" void kernel_launch(void* const* d_in, const int* in_sizes, int n_in,
                              void* d_out, int out_size, void* d_ws, size_t ws_size,
                              hipStream_t stream) {
    const float* x      = (const float*)d_in[0];
    const float* W_qkv  = (const float*)d_in[1];
    const float* b_qkv  = (const float*)d_in[2];
    const float* W_proj = (const float*)d_in[3];
    const float* b_proj = (const float*)d_in[4];
    float* out = (float*)d_out;

    char* ws = (char*)d_ws;
    ushort_t* xb     = (ushort_t*)(ws);                        // 4096x1024 bf16
    ushort_t* WqkvT  = (ushort_t*)(ws + (size_t)8  * 1048576); // 3072x1024 bf16
    ushort_t* QKVb   = (ushort_t*)(ws + (size_t)14 * 1048576); // 4096x3072 bf16
    ushort_t* AO     = (ushort_t*)(ws + (size_t)38 * 1048576); // 4096x1024 bf16
    ushort_t* WprojT = (ushort_t*)(ws + (size_t)46 * 1048576); // 1024x1024 bf16

    prep<<<8192, 256, 0, stream>>>(x, xb, W_qkv, WqkvT, W_proj, WprojT);
    gemm_qkv<<<256, 512, 0, stream>>>(xb, WqkvT, b_qkv, QKVb, 3072, 1024);
    fenwick_attn<<<2048, 256, 0, stream>>>(QKVb, AO);
    gemm_proj<<<256, 256, 0, stream>>>(AO, WprojT, b_proj, out, 1024, 1024);
}

// Round 4
// 147.464 us; speedup vs baseline: 1.4907x; 1.0043x over previous
//
#include <hip/hip_runtime.h>
#include <hip/hip_bf16.h>

// FenwickLogLinearAttention: B=2,T=2048,C=1024,H=16,Dh=64
// R7: qkv phase-merge 8->4 phases/iter (24 MFMA/phase). R6 counters showed qkv
//     = 43us with MfmaUtil 21%, zero bank conflicts, HBM 1 TB/s -> per-phase
//     fixed overhead (~700cy x 64 phases) dominates. Merging halves the number
//     of barrier/wait events per MFMA. Ledger re-derived: stages P1:2 P2:5
//     P3:2 P4:5, vmcnt(5) at P2/P4 ends (oldest-7 = next tile), tail drains
//     vmcnt(0). attn/proj/prep unchanged from R6.
// ws layout (bytes): xb@0 (8M) | WqkvT@8M (6M) | QKVb@14M (24M) | AO@38M (8M) | WprojT@46M (2M)

typedef unsigned short ushort_t;
typedef __attribute__((ext_vector_type(8))) short s16x8;
typedef __attribute__((ext_vector_type(4))) float f32x4;

#define T_SEQ 2048
#define C_DIM 1024
#define HEADS 16

__device__ __forceinline__ ushort_t f2bf(float f) {
    union { float f; unsigned u; } v{f};
    unsigned r = v.u + 0x7FFFu + ((v.u >> 16) & 1u);   // RNE
    return (ushort_t)(r >> 16);
}
__device__ __forceinline__ float bf2f(ushort_t u) {
    union { unsigned u; float f; } v{((unsigned)u) << 16};
    return v.f;
}

__device__ __forceinline__ void async16(const ushort_t* g, ushort_t* l) {
    __builtin_amdgcn_global_load_lds(
        (const __attribute__((address_space(1))) void*)g,
        (__attribute__((address_space(3))) void*)l, 16, 0, 0);
}

// ---------------- merged prep: cvt(x)->bf16 + two weight transposes ----------------
__global__ void prep(const float* __restrict__ x, ushort_t* __restrict__ xb,
                     const float* __restrict__ Wq, ushort_t* __restrict__ WqT,
                     const float* __restrict__ Wp, ushort_t* __restrict__ WpT) {
    const int bid = blockIdx.x;
    const int tid = threadIdx.x;
    if (bid < 4096) {
        const int i = bid * 256 + tid;
        float4 f = ((const float4*)x)[i];
        ushort4 o;
        o.x = f2bf(f.x); o.y = f2bf(f.y); o.z = f2bf(f.z); o.w = f2bf(f.w);
        ((ushort4*)xb)[i] = o;
    } else {
        __shared__ ushort_t tile[32][33];
        const float* W; ushort_t* WT; int N, nb, kb;
        if (bid < 7168) {
            const int tb = bid - 4096;
            W = Wq; WT = WqT; N = 3072; nb = (tb % 96) * 32; kb = (tb / 96) * 32;
        } else {
            const int tb = bid - 7168;
            W = Wp; WT = WpT; N = 1024; nb = (tb & 31) * 32; kb = (tb >> 5) * 32;
        }
        const int tx = tid & 31, ty = tid >> 5;
        #pragma unroll
        for (int i = ty; i < 32; i += 8)
            tile[i][tx] = f2bf(W[(size_t)(kb + i) * N + nb + tx]);
        __syncthreads();
        #pragma unroll
        for (int i = ty; i < 32; i += 8)
            WT[(size_t)(nb + i) * 1024 + kb + tx] = tile[tx][i];
    }
}

// ---------------- QKV GEMM: 256x192 tile, BK=64, 4-phase counted-vmcnt ----------------
#define BAR()  do { __builtin_amdgcn_sched_barrier(0); __builtin_amdgcn_s_barrier(); \
                    __builtin_amdgcn_sched_barrier(0); } while (0)
#define WAIT_LGKM0() do { asm volatile("s_waitcnt lgkmcnt(0)" ::: "memory"); \
                          __builtin_amdgcn_sched_barrier(0); } while (0)
#define WAIT_VM(n)  asm volatile("s_waitcnt vmcnt(" #n ")" ::: "memory")

#define SA(kt, u, dst) async16(Ag + (size_t)(u) * rstep + (size_t)(kt) * 64, \
                               (dst) + (u) * 4096 + wave * 512)
#define SB(kt, u, dst) async16(Bg + (size_t)(u) * rstep + (size_t)(kt) * 64, \
                               (dst) + (u) * 4096 + wave * 512)

#define LDA_FRAG(buf, i, kh) (*(const s16x8*)((buf) + ((wm << 7) + (i) * 16 + lrow) * 64 \
                               + ((((kh) * 4 + quad) ^ d3) << 3)))
#define LDB_FRAG(buf, j, kh) (*(const s16x8*)((buf) + (wn * 48 + (j) * 16 + lrow) * 64 \
                               + ((((kh) * 4 + quad) ^ d3) << 3)))

// one merged phase: M-frags F0..F0+3 x all 3 N-frags x K=64 (24 MFMA)
#define PHASE2(lAb, lBb, F0, LOADB, STAGES, ENDWAIT)                            \
  {                                                                             \
    s16x8 af[4][2];                                                             \
    _Pragma("unroll") for (int ii = 0; ii < 4; ++ii)                            \
      _Pragma("unroll") for (int kh = 0; kh < 2; ++kh)                          \
        af[ii][kh] = LDA_FRAG(lAb, (F0) + ii, kh);                              \
    if (LOADB) {                                                                \
      _Pragma("unroll") for (int j = 0; j < 3; ++j)                             \
        _Pragma("unroll") for (int kh = 0; kh < 2; ++kh)                        \
          bf[j][kh] = LDB_FRAG(lBb, j, kh);                                     \
    }                                                                           \
    STAGES;                                                                     \
    BAR();                                                                      \
    WAIT_LGKM0();                                                               \
    __builtin_amdgcn_s_setprio(1);                                              \
    _Pragma("unroll") for (int ii = 0; ii < 4; ++ii)                            \
      _Pragma("unroll") for (int j = 0; j < 3; ++j)                             \
        _Pragma("unroll") for (int kh = 0; kh < 2; ++kh)                        \
          acc[(F0) + ii][j] = __builtin_amdgcn_mfma_f32_16x16x32_bf16(          \
              af[ii][kh], bf[j][kh], acc[(F0) + ii][j], 0, 0, 0);               \
    __builtin_amdgcn_s_setprio(0);                                              \
    ENDWAIT;                                                                    \
    BAR();                                                                      \
  }

__global__ __launch_bounds__(512, 2)
void gemm_qkv(const ushort_t* __restrict__ A, const ushort_t* __restrict__ BT,
              const float* __restrict__ bias, ushort_t* __restrict__ C,
              int N, int K) {
    __shared__ ushort_t lds[57344];          // 112 KiB

    const int tid  = threadIdx.x;
    const int wave = tid >> 6;
    const int lane = tid & 63;
    const int wm   = wave >> 2;              // 0..1  (M half)
    const int wn   = wave & 3;               // 0..3  (N quarter: 48 cols)
    const int lrow = lane & 15;
    const int quad = lane >> 4;
    const int d3   = lrow & 7;
    const int crow = lane >> 3;
    const int gcol = (((lane & 7) ^ crow) << 3);   // pre-swizzled global k-group

    // XCD region swizzle: XCD (bid&7) owns a 4-rowblk x 8-colblk region.
    const int bid    = blockIdx.x;
    const int xcd    = bid & 7;
    const int q      = bid >> 3;                   // [0,32)
    const int rowblk = ((xcd & 3) << 2) + (q & 3); // [0,16)
    const int colblk = ((xcd >> 2) << 3) + (q >> 2);// [0,16)
    const int row0   = rowblk * 256;
    const int col0   = colblk * 192;

    ushort_t* const lA0 = lds;                       // A buf0: 16384 el
    ushort_t* const lB0 = lds + 16384;               // B buf0: 12288 el
    ushort_t* const lA1 = lds + 28672;               // A buf1
    ushort_t* const lB1 = lds + 45056;               // B buf1

    const ushort_t* Ag = A  + (size_t)(row0 + wave * 8 + crow) * K + gcol;
    const ushort_t* Bg = BT + (size_t)(col0 + wave * 8 + crow) * K + gcol;
    const size_t rstep = (size_t)64 * K;             // 64-row stage unit

    f32x4 acc[8][3] = {};
    s16x8 bf[3][2];

    // prologue: tile0 fully (7 loads), then tile1 partial (5, in steady-P4 order)
    SA(0, 0, lA0); SA(0, 1, lA0); SA(0, 2, lA0); SA(0, 3, lA0);
    SB(0, 0, lB0); SB(0, 1, lB0); SB(0, 2, lB0);
    SB(1, 0, lB1); SB(1, 1, lB1); SB(1, 2, lB1); SA(1, 0, lA1); SA(1, 2, lA1);
    WAIT_VM(5);
    BAR();

    const int nt = K >> 6;                           // 16 K-tiles
    for (int t = 0; t < nt; t += 2) {
        const bool s2 = (t + 2) < nt;                // nt even -> s2==s3
        // P1: buf0 frags 0-3 (+bf); stage A(t+1) u1,u3 -> lA1 (free since prev P4)
        PHASE2(lA0, lB0, 0, true, { SA(t + 1, 1, lA1); SA(t + 1, 3, lA1); }, {});
        // P2: buf0 frags 4-7; stage B(t+2)->lB0 (free after P1), A(t+2)u0,u2->lA0
        //     (u0,u2 free after P1); endwait: oldest 7 = tile t+1 landed
        PHASE2(lA0, lB0, 4, false,
               { if (s2) { SB(t + 2, 0, lB0); SB(t + 2, 1, lB0); SB(t + 2, 2, lB0);
                           SA(t + 2, 0, lA0); SA(t + 2, 2, lA0); } },
               { if (s2) { WAIT_VM(5); } else { WAIT_VM(0); } });
        // P3: buf1 frags 0-3 (+bf); stage A(t+2) u1,u3 -> lA0 (u1,u3 free after P2)
        PHASE2(lA1, lB1, 0, true, { if (s2) { SA(t + 2, 1, lA0); SA(t + 2, 3, lA0); } }, {});
        // P4: buf1 frags 4-7; stage B(t+3)->lB1 (free after P3), A(t+3)u0,u2->lA1
        //     (u0,u2 free after P3); endwait: oldest 7 = tile t+2 landed
        PHASE2(lA1, lB1, 4, false,
               { if (s2) { SB(t + 3, 0, lB1); SB(t + 3, 1, lB1); SB(t + 3, 2, lB1);
                           SA(t + 3, 0, lA1); SA(t + 3, 2, lA1); } },
               { if (s2) { WAIT_VM(5); } });
    }

    // D mapping: col=lane&15, row=quad*4+reg (m89-verified)
    #pragma unroll
    for (int i = 0; i < 8; ++i) {
        #pragma unroll
        for (int j = 0; j < 3; ++j) {
            const int col = col0 + wn * 48 + j * 16 + lrow;
            const float bv = bias[col];
            #pragma unroll
            for (int r = 0; r < 4; ++r) {
                const int row = row0 + (wm << 7) + i * 16 + quad * 4 + r;
                C[(size_t)row * N + col] = f2bf(acc[i][j][r] + bv);
            }
        }
    }
}

// ---------------- proj GEMM: 128x128 tile, BK=64, swizzled LDS, fp32 out ----------------
// 256 blocks = 1/CU; XCD (bid&7) owns rowblks [4*xcd, 4*xcd+4) x all 8 colblks:
// per-XCD working set A 1MB + B 2.1MB = 3.1MB < 4MB L2 -> re-reads are L2 hits.
__global__ void gemm_proj(const ushort_t* __restrict__ A, const ushort_t* __restrict__ BT,
                          const float* __restrict__ bias, float* __restrict__ C,
                          int N, int K) {
    __shared__ ushort_t lsA[128 * 64];
    __shared__ ushort_t lsB[128 * 64];

    const int tid  = threadIdx.x;
    const int wave = tid >> 6;
    const int lane = tid & 63;

    const int bid  = blockIdx.x;
    const int xcd  = bid & 7;
    const int q    = bid >> 3;                 // [0,32)
    const int row0 = (xcd * 4 + (q & 3)) * 128;   // rowblk [0,32)
    const int col0 = (q >> 2) * 128;              // colblk [0,8)

    const int wr   = (wave >> 1) * 64;
    const int wc   = (wave & 1) * 64;
    const int lrow = lane & 15;
    const int quad = lane >> 4;
    const int crow = lane >> 3;
    const int gcol = ((lane & 7) ^ crow) * 8;
    const int d3   = lrow & 7;

    f32x4 acc[4][4] = {};

    for (int k0 = 0; k0 < K; k0 += 64) {
        #pragma unroll
        for (int it = 0; it < 4; ++it) {
            const int chunk = it * 4 + wave;           // 16 chunks x 1KB each
            const int r = chunk * 8 + crow;
            async16(A  + (size_t)(row0 + r) * K + (k0 + gcol), lsA + chunk * 512);
            async16(BT + (size_t)(col0 + r) * K + (k0 + gcol), lsB + chunk * 512);
        }
        __syncthreads();   // drains vmcnt -> staged data visible
        #pragma unroll
        for (int kk = 0; kk < 64; kk += 32) {
            const int g = (kk >> 3) + quad;
            const int slot = (g ^ d3) << 3;
            s16x8 af[4], bfr[4];
            #pragma unroll
            for (int i = 0; i < 4; ++i)
                af[i] = *(const s16x8*)(lsA + (wr + i * 16 + lrow) * 64 + slot);
            #pragma unroll
            for (int j = 0; j < 4; ++j)
                bfr[j] = *(const s16x8*)(lsB + (wc + j * 16 + lrow) * 64 + slot);
            #pragma unroll
            for (int i = 0; i < 4; ++i)
                #pragma unroll
                for (int j = 0; j < 4; ++j)
                    acc[i][j] = __builtin_amdgcn_mfma_f32_16x16x32_bf16(
                        af[i], bfr[j], acc[i][j], 0, 0, 0);
        }
        __syncthreads();
    }

    #pragma unroll
    for (int i = 0; i < 4; ++i) {
        #pragma unroll
        for (int j = 0; j < 4; ++j) {
            const int col = col0 + wc + j * 16 + lrow;
            const float bv = bias[col];
            #pragma unroll
            for (int r = 0; r < 4; ++r) {
                const int row = row0 + wr + i * 16 + quad * 4 + r;
                C[(size_t)row * N + col] = acc[i][j][r] + bv;
            }
        }
    }
}

// ---------------- sparse Fenwick attention ----------------
// bh-per-XCD swizzle: XCD x serves bh in {x, x+8, x+16, x+24} (64 blocks each);
// per-XCD K/V working set = 4 x 512KB = 2MB < 4MB L2.
__global__ void fenwick_attn(const ushort_t* __restrict__ QKV, ushort_t* __restrict__ AO) {
    const int lane = threadIdx.x & 63;
    const int bid  = blockIdx.x;
    const int xcd  = bid & 7;
    const int q    = bid >> 3;                       // [0,256)
    const int bh   = xcd + ((q >> 6) << 3);          // [0,32)
    const int tile = ((q & 63) << 2) + (threadIdx.x >> 6); // [0,256)
    const int h    = bh & (HEADS - 1);
    const int b    = bh >> 4;
    const int tl   = lane >> 3;
    const int g    = lane & 7;
    const int t    = tile * 8 + tl;

    const ushort_t* base = QKV + (size_t)(b * T_SEQ) * 3072 + h * 64 + g * 8;

    float qf[8];
    {
        s16x8 qv = *(const s16x8*)(base + (size_t)t * 3072);
        #pragma unroll
        for (int e = 0; e < 8; ++e) qf[e] = bf2f((ushort_t)qv[e]);
    }

    float logit[12];
    int   pos[12];
    float mx = -1e30f;
    #pragma unroll
    for (int s = 0; s < 12; ++s) {
        const int step = (s == 0) ? 0 : (1 << (s - 1));
        const bool act = (step <= t);
        const int p = act ? (t - step) : t;
        pos[s] = p;
        s16x8 kv = *(const s16x8*)(base + (size_t)p * 3072 + 1024);
        float l = 0.f;
        #pragma unroll
        for (int e = 0; e < 8; ++e) l = fmaf(qf[e], bf2f((ushort_t)kv[e]), l);
        l += __shfl_xor(l, 1, 64);
        l += __shfl_xor(l, 2, 64);
        l += __shfl_xor(l, 4, 64);
        l *= 0.125f;                       // Dh^-0.5
        logit[s] = act ? l : -1e30f;
        mx = fmaxf(mx, logit[s]);
    }

    float denom = 0.f;
    float ov[8] = {};
    #pragma unroll
    for (int s = 0; s < 12; ++s) {
        const float w = __expf(logit[s] - mx);
        denom += w;
        s16x8 vv = *(const s16x8*)(base + (size_t)pos[s] * 3072 + 2048);
        #pragma unroll
        for (int e = 0; e < 8; ++e) ov[e] = fmaf(w, bf2f((ushort_t)vv[e]), ov[e]);
    }

    const float inv = 1.f / denom;
    s16x8 os;
    #pragma unroll
    for (int e = 0; e < 8; ++e) os[e] = (short)f2bf(ov[e] * inv);
    *(s16x8*)(AO + (size_t)(b * T_SEQ + t) * C_DIM + h * 64 + g * 8) = os;
}

extern "C" void kernel_launch(void* const* d_in, const int* in_sizes, int n_in,
                              void* d_out, int out_size, void* d_ws, size_t ws_size,
                              hipStream_t stream) {
    const float* x      = (const float*)d_in[0];
    const float* W_qkv  = (const float*)d_in[1];
    const float* b_qkv  = (const float*)d_in[2];
    const float* W_proj = (const float*)d_in[3];
    const float* b_proj = (const float*)d_in[4];
    float* out = (float*)d_out;

    char* ws = (char*)d_ws;
    ushort_t* xb     = (ushort_t*)(ws);                        // 4096x1024 bf16
    ushort_t* WqkvT  = (ushort_t*)(ws + (size_t)8  * 1048576); // 3072x1024 bf16
    ushort_t* QKVb   = (ushort_t*)(ws + (size_t)14 * 1048576); // 4096x3072 bf16
    ushort_t* AO     = (ushort_t*)(ws + (size_t)38 * 1048576); // 4096x1024 bf16
    ushort_t* WprojT = (ushort_t*)(ws + (size_t)46 * 1048576); // 1024x1024 bf16

    prep<<<8192, 256, 0, stream>>>(x, xb, W_qkv, WqkvT, W_proj, WprojT);
    gemm_qkv<<<256, 512, 0, stream>>>(xb, WqkvT, b_qkv, QKVb, 3072, 1024);
    fenwick_attn<<<2048, 256, 0, stream>>>(QKVb, AO);
    gemm_proj<<<256, 256, 0, stream>>>(AO, WprojT, b_proj, out, 1024, 1024);
}

// Round 5
// 145.502 us; speedup vs baseline: 1.5108x; 1.0135x over previous
//
#include <hip/hip_runtime.h>
#include <hip/hip_bf16.h>

// FenwickLogLinearAttention: B=2,T=2048,C=1024,H=16,Dh=64
// R8: kill the LDS|MFMA pipe serialization. qkv: ONE barrier per phase
//     (reads;stages;vmcnt;BAR;lgkm;MFMA) — vmcnt moved PRE-barrier so it stays
//     collective; post-MFMA barrier removed (ledger re-audited: every stage
//     lands >=1 barrier after its target region's reads are issued; LDS
//     services in arrival order). Waves skew: fast waves issue next reads
//     while slow waves MFMA -> pipes overlap. proj: double-buffered, stage
//     t+1 issued BEFORE compute, single __syncthreads per tile (implicit
//     vmcnt0 drain = collective). prep/attn unchanged.
// ws layout (bytes): xb@0 (8M) | WqkvT@8M (6M) | QKVb@14M (24M) | AO@38M (8M) | WprojT@46M (2M)

typedef unsigned short ushort_t;
typedef __attribute__((ext_vector_type(8))) short s16x8;
typedef __attribute__((ext_vector_type(4))) float f32x4;

#define T_SEQ 2048
#define C_DIM 1024
#define HEADS 16

__device__ __forceinline__ ushort_t f2bf(float f) {
    union { float f; unsigned u; } v{f};
    unsigned r = v.u + 0x7FFFu + ((v.u >> 16) & 1u);   // RNE
    return (ushort_t)(r >> 16);
}
__device__ __forceinline__ float bf2f(ushort_t u) {
    union { unsigned u; float f; } v{((unsigned)u) << 16};
    return v.f;
}

__device__ __forceinline__ void async16(const ushort_t* g, ushort_t* l) {
    __builtin_amdgcn_global_load_lds(
        (const __attribute__((address_space(1))) void*)g,
        (__attribute__((address_space(3))) void*)l, 16, 0, 0);
}

// ---------------- merged prep: cvt(x)->bf16 + two weight transposes ----------------
__global__ void prep(const float* __restrict__ x, ushort_t* __restrict__ xb,
                     const float* __restrict__ Wq, ushort_t* __restrict__ WqT,
                     const float* __restrict__ Wp, ushort_t* __restrict__ WpT) {
    const int bid = blockIdx.x;
    const int tid = threadIdx.x;
    if (bid < 4096) {
        const int i = bid * 256 + tid;
        float4 f = ((const float4*)x)[i];
        ushort4 o;
        o.x = f2bf(f.x); o.y = f2bf(f.y); o.z = f2bf(f.z); o.w = f2bf(f.w);
        ((ushort4*)xb)[i] = o;
    } else {
        __shared__ ushort_t tile[32][33];
        const float* W; ushort_t* WT; int N, nb, kb;
        if (bid < 7168) {
            const int tb = bid - 4096;
            W = Wq; WT = WqT; N = 3072; nb = (tb % 96) * 32; kb = (tb / 96) * 32;
        } else {
            const int tb = bid - 7168;
            W = Wp; WT = WpT; N = 1024; nb = (tb & 31) * 32; kb = (tb >> 5) * 32;
        }
        const int tx = tid & 31, ty = tid >> 5;
        #pragma unroll
        for (int i = ty; i < 32; i += 8)
            tile[i][tx] = f2bf(W[(size_t)(kb + i) * N + nb + tx]);
        __syncthreads();
        #pragma unroll
        for (int i = ty; i < 32; i += 8)
            WT[(size_t)(nb + i) * 1024 + kb + tx] = tile[tx][i];
    }
}

// ---------------- QKV GEMM: 256x192 tile, BK=64, 4-phase single-barrier ----------------
#define WAIT_LGKM0() do { asm volatile("s_waitcnt lgkmcnt(0)" ::: "memory"); \
                          __builtin_amdgcn_sched_barrier(0); } while (0)
#define WAIT_VM(n)  asm volatile("s_waitcnt vmcnt(" #n ")" ::: "memory")

#define SA(kt, u, dst) async16(Ag + (size_t)(u) * rstep + (size_t)(kt) * 64, \
                               (dst) + (u) * 4096 + wave * 512)
#define SB(kt, u, dst) async16(Bg + (size_t)(u) * rstep + (size_t)(kt) * 64, \
                               (dst) + (u) * 4096 + wave * 512)

#define LDA_FRAG(buf, i, kh) (*(const s16x8*)((buf) + ((wm << 7) + (i) * 16 + lrow) * 64 \
                               + ((((kh) * 4 + quad) ^ d3) << 3)))
#define LDB_FRAG(buf, j, kh) (*(const s16x8*)((buf) + (wn * 48 + (j) * 16 + lrow) * 64 \
                               + ((((kh) * 4 + quad) ^ d3) << 3)))

// one phase: reads; stages; (collective-to-be vmcnt); BARRIER; lgkm; 24 MFMA.
// No trailing barrier: waves skew into the next phase's read region while
// others finish MFMA -> LDS pipe and MFMA pipe overlap.
#define PHASE3(lAb, lBb, F0, LOADB, STAGES, PREBAR)                             \
  {                                                                             \
    s16x8 af[4][2];                                                             \
    _Pragma("unroll") for (int ii = 0; ii < 4; ++ii)                            \
      _Pragma("unroll") for (int kh = 0; kh < 2; ++kh)                          \
        af[ii][kh] = LDA_FRAG(lAb, (F0) + ii, kh);                              \
    if (LOADB) {                                                                \
      _Pragma("unroll") for (int j = 0; j < 3; ++j)                             \
        _Pragma("unroll") for (int kh = 0; kh < 2; ++kh)                        \
          bf[j][kh] = LDB_FRAG(lBb, j, kh);                                     \
    }                                                                           \
    STAGES;                                                                     \
    PREBAR;                                                                     \
    __builtin_amdgcn_s_barrier();                                               \
    WAIT_LGKM0();                                                               \
    __builtin_amdgcn_s_setprio(1);                                              \
    _Pragma("unroll") for (int ii = 0; ii < 4; ++ii)                            \
      _Pragma("unroll") for (int j = 0; j < 3; ++j)                             \
        _Pragma("unroll") for (int kh = 0; kh < 2; ++kh)                        \
          acc[(F0) + ii][j] = __builtin_amdgcn_mfma_f32_16x16x32_bf16(          \
              af[ii][kh], bf[j][kh], acc[(F0) + ii][j], 0, 0, 0);               \
    __builtin_amdgcn_s_setprio(0);                                              \
  }

__global__ __launch_bounds__(512, 2)
void gemm_qkv(const ushort_t* __restrict__ A, const ushort_t* __restrict__ BT,
              const float* __restrict__ bias, ushort_t* __restrict__ C,
              int N, int K) {
    __shared__ ushort_t lds[57344];          // 112 KiB

    const int tid  = threadIdx.x;
    const int wave = tid >> 6;
    const int lane = tid & 63;
    const int wm   = wave >> 2;              // 0..1  (M half)
    const int wn   = wave & 3;               // 0..3  (N quarter: 48 cols)
    const int lrow = lane & 15;
    const int quad = lane >> 4;
    const int d3   = lrow & 7;
    const int crow = lane >> 3;
    const int gcol = (((lane & 7) ^ crow) << 3);   // pre-swizzled global k-group

    // XCD region swizzle: XCD (bid&7) owns a 4-rowblk x 8-colblk region.
    const int bid    = blockIdx.x;
    const int xcd    = bid & 7;
    const int q      = bid >> 3;                   // [0,32)
    const int rowblk = ((xcd & 3) << 2) + (q & 3); // [0,16)
    const int colblk = ((xcd >> 2) << 3) + (q >> 2);// [0,16)
    const int row0   = rowblk * 256;
    const int col0   = colblk * 192;

    ushort_t* const lA0 = lds;                       // A buf0: 16384 el
    ushort_t* const lB0 = lds + 16384;               // B buf0: 12288 el
    ushort_t* const lA1 = lds + 28672;               // A buf1
    ushort_t* const lB1 = lds + 45056;               // B buf1

    const ushort_t* Ag = A  + (size_t)(row0 + wave * 8 + crow) * K + gcol;
    const ushort_t* Bg = BT + (size_t)(col0 + wave * 8 + crow) * K + gcol;
    const size_t rstep = (size_t)64 * K;             // 64-row stage unit

    f32x4 acc[8][3] = {};
    s16x8 bf[3][2];

    // prologue: tile0 fully (7 loads), then tile1 partial (5, steady-P4 order)
    SA(0, 0, lA0); SA(0, 1, lA0); SA(0, 2, lA0); SA(0, 3, lA0);
    SB(0, 0, lB0); SB(0, 1, lB0); SB(0, 2, lB0);
    SB(1, 0, lB1); SB(1, 1, lB1); SB(1, 2, lB1); SA(1, 0, lA1); SA(1, 2, lA1);
    WAIT_VM(5);
    __builtin_amdgcn_s_barrier();

    // vmcnt ledger (per wave, steady state): enter P1 with 5 outstanding
    // (tile t+1 partial {B0,B1,B2,A0,A2}); P1 +2 (t+1 A1,A3) = 7;
    // P2 +5 (t+2 partial) = 12, vmcnt(5) pre-BAR -> tile t+1 fully landed,
    // collectivized by BAR_P2, read in P3/P4. Mirror for P3/P4 -> tile t+2.
    const int nt = K >> 6;                           // 16 K-tiles
    for (int t = 0; t < nt; t += 2) {
        const bool s2 = (t + 2) < nt;
        // P1: buf0 frags 0-3 (+bf); stage A(t+1) u1,u3 -> lA1
        PHASE3(lA0, lB0, 0, true, { SA(t + 1, 1, lA1); SA(t + 1, 3, lA1); }, {});
        // P2: buf0 frags 4-7; stage t+2 partial -> lB0, lA0 u0,u2 (read in P1);
        //     vmcnt(5) pre-BAR: tile t+1 landed (tail: drain all for tile t+1)
        PHASE3(lA0, lB0, 4, false,
               { if (s2) { SB(t + 2, 0, lB0); SB(t + 2, 1, lB0); SB(t + 2, 2, lB0);
                           SA(t + 2, 0, lA0); SA(t + 2, 2, lA0); } },
               { if (s2) { WAIT_VM(5); } else { WAIT_VM(0); } });
        // P3: buf1 frags 0-3 (+bf); stage A(t+2) u1,u3 -> lA0 (read in P2)
        PHASE3(lA1, lB1, 0, true, { if (s2) { SA(t + 2, 1, lA0); SA(t + 2, 3, lA0); } }, {});
        // P4: buf1 frags 4-7; stage t+3 partial -> lB1, lA1 u0,u2 (read in P3);
        //     vmcnt(5) pre-BAR: tile t+2 landed
        PHASE3(lA1, lB1, 4, false,
               { if (s2) { SB(t + 3, 0, lB1); SB(t + 3, 1, lB1); SB(t + 3, 2, lB1);
                           SA(t + 3, 0, lA1); SA(t + 3, 2, lA1); } },
               { if (s2) { WAIT_VM(5); } });
    }

    // D mapping: col=lane&15, row=quad*4+reg (m89-verified)
    #pragma unroll
    for (int i = 0; i < 8; ++i) {
        #pragma unroll
        for (int j = 0; j < 3; ++j) {
            const int col = col0 + wn * 48 + j * 16 + lrow;
            const float bv = bias[col];
            #pragma unroll
            for (int r = 0; r < 4; ++r) {
                const int row = row0 + (wm << 7) + i * 16 + quad * 4 + r;
                C[(size_t)row * N + col] = f2bf(acc[i][j][r] + bv);
            }
        }
    }
}

// ---------------- proj GEMM: 128x128 tile, BK=64, DOUBLE-buffered, 1 sync/tile ----------------
// Stage t+1 issued BEFORE compute(t); __syncthreads (implicit vmcnt0+lgkm0
// drain, collective) once per tile. XCD region swizzle as R6.
#define PSTAGE(t, b) do {                                                        \
    _Pragma("unroll") for (int it = 0; it < 4; ++it) {                           \
        const int chunk = it * 4 + wave;                                         \
        const int r = chunk * 8 + crow;                                          \
        async16(A  + (size_t)(row0 + r) * K + ((t) * 64 + gcol), lsA[b] + chunk * 512); \
        async16(BT + (size_t)(col0 + r) * K + ((t) * 64 + gcol), lsB[b] + chunk * 512); \
    }                                                                            \
} while (0)

__global__ void gemm_proj(const ushort_t* __restrict__ A, const ushort_t* __restrict__ BT,
                          const float* __restrict__ bias, float* __restrict__ C,
                          int N, int K) {
    __shared__ ushort_t lsA[2][128 * 64];
    __shared__ ushort_t lsB[2][128 * 64];

    const int tid  = threadIdx.x;
    const int wave = tid >> 6;
    const int lane = tid & 63;

    const int bid  = blockIdx.x;
    const int xcd  = bid & 7;
    const int q    = bid >> 3;                 // [0,32)
    const int row0 = (xcd * 4 + (q & 3)) * 128;   // rowblk [0,32)
    const int col0 = (q >> 2) * 128;              // colblk [0,8)

    const int wr   = (wave >> 1) * 64;
    const int wc   = (wave & 1) * 64;
    const int lrow = lane & 15;
    const int quad = lane >> 4;
    const int crow = lane >> 3;
    const int gcol = ((lane & 7) ^ crow) * 8;
    const int d3   = lrow & 7;

    f32x4 acc[4][4] = {};

    const int nt = K >> 6;                     // 16 K-tiles
    int cur = 0;
    PSTAGE(0, 0);
    __syncthreads();                            // drains vmcnt -> tile0 visible
    for (int t = 0; t < nt; ++t) {
        if (t + 1 < nt) PSTAGE(t + 1, cur ^ 1); // overlaps compute below
        #pragma unroll
        for (int kk = 0; kk < 64; kk += 32) {
            const int g = (kk >> 3) + quad;
            const int slot = (g ^ d3) << 3;
            s16x8 af[4], bfr[4];
            #pragma unroll
            for (int i = 0; i < 4; ++i)
                af[i] = *(const s16x8*)(lsA[cur] + (wr + i * 16 + lrow) * 64 + slot);
            #pragma unroll
            for (int j = 0; j < 4; ++j)
                bfr[j] = *(const s16x8*)(lsB[cur] + (wc + j * 16 + lrow) * 64 + slot);
            #pragma unroll
            for (int i = 0; i < 4; ++i)
                #pragma unroll
                for (int j = 0; j < 4; ++j)
                    acc[i][j] = __builtin_amdgcn_mfma_f32_16x16x32_bf16(
                        af[i], bfr[j], acc[i][j], 0, 0, 0);
        }
        __syncthreads();                        // one barrier per tile
        cur ^= 1;
    }

    #pragma unroll
    for (int i = 0; i < 4; ++i) {
        #pragma unroll
        for (int j = 0; j < 4; ++j) {
            const int col = col0 + wc + j * 16 + lrow;
            const float bv = bias[col];
            #pragma unroll
            for (int r = 0; r < 4; ++r) {
                const int row = row0 + wr + i * 16 + quad * 4 + r;
                C[(size_t)row * N + col] = acc[i][j][r] + bv;
            }
        }
    }
}

// ---------------- sparse Fenwick attention ----------------
// bh-per-XCD swizzle: XCD x serves bh in {x, x+8, x+16, x+24} (64 blocks each);
// per-XCD K/V working set = 4 x 512KB = 2MB < 4MB L2.
__global__ void fenwick_attn(const ushort_t* __restrict__ QKV, ushort_t* __restrict__ AO) {
    const int lane = threadIdx.x & 63;
    const int bid  = blockIdx.x;
    const int xcd  = bid & 7;
    const int q    = bid >> 3;                       // [0,256)
    const int bh   = xcd + ((q >> 6) << 3);          // [0,32)
    const int tile = ((q & 63) << 2) + (threadIdx.x >> 6); // [0,256)
    const int h    = bh & (HEADS - 1);
    const int b    = bh >> 4;
    const int tl   = lane >> 3;
    const int g    = lane & 7;
    const int t    = tile * 8 + tl;

    const ushort_t* base = QKV + (size_t)(b * T_SEQ) * 3072 + h * 64 + g * 8;

    float qf[8];
    {
        s16x8 qv = *(const s16x8*)(base + (size_t)t * 3072);
        #pragma unroll
        for (int e = 0; e < 8; ++e) qf[e] = bf2f((ushort_t)qv[e]);
    }

    float logit[12];
    int   pos[12];
    float mx = -1e30f;
    #pragma unroll
    for (int s = 0; s < 12; ++s) {
        const int step = (s == 0) ? 0 : (1 << (s - 1));
        const bool act = (step <= t);
        const int p = act ? (t - step) : t;
        pos[s] = p;
        s16x8 kv = *(const s16x8*)(base + (size_t)p * 3072 + 1024);
        float l = 0.f;
        #pragma unroll
        for (int e = 0; e < 8; ++e) l = fmaf(qf[e], bf2f((ushort_t)kv[e]), l);
        l += __shfl_xor(l, 1, 64);
        l += __shfl_xor(l, 2, 64);
        l += __shfl_xor(l, 4, 64);
        l *= 0.125f;                       // Dh^-0.5
        logit[s] = act ? l : -1e30f;
        mx = fmaxf(mx, logit[s]);
    }

    float denom = 0.f;
    float ov[8] = {};
    #pragma unroll
    for (int s = 0; s < 12; ++s) {
        const float w = __expf(logit[s] - mx);
        denom += w;
        s16x8 vv = *(const s16x8*)(base + (size_t)pos[s] * 3072 + 2048);
        #pragma unroll
        for (int e = 0; e < 8; ++e) ov[e] = fmaf(w, bf2f((ushort_t)vv[e]), ov[e]);
    }

    const float inv = 1.f / denom;
    s16x8 os;
    #pragma unroll
    for (int e = 0; e < 8; ++e) os[e] = (short)f2bf(ov[e] * inv);
    *(s16x8*)(AO + (size_t)(b * T_SEQ + t) * C_DIM + h * 64 + g * 8) = os;
}

extern "C" void kernel_launch(void* const* d_in, const int* in_sizes, int n_in,
                              void* d_out, int out_size, void* d_ws, size_t ws_size,
                              hipStream_t stream) {
    const float* x      = (const float*)d_in[0];
    const float* W_qkv  = (const float*)d_in[1];
    const float* b_qkv  = (const float*)d_in[2];
    const float* W_proj = (const float*)d_in[3];
    const float* b_proj = (const float*)d_in[4];
    float* out = (float*)d_out;

    char* ws = (char*)d_ws;
    ushort_t* xb     = (ushort_t*)(ws);                        // 4096x1024 bf16
    ushort_t* WqkvT  = (ushort_t*)(ws + (size_t)8  * 1048576); // 3072x1024 bf16
    ushort_t* QKVb   = (ushort_t*)(ws + (size_t)14 * 1048576); // 4096x3072 bf16
    ushort_t* AO     = (ushort_t*)(ws + (size_t)38 * 1048576); // 4096x1024 bf16
    ushort_t* WprojT = (ushort_t*)(ws + (size_t)46 * 1048576); // 1024x1024 bf16

    prep<<<8192, 256, 0, stream>>>(x, xb, W_qkv, WqkvT, W_proj, WprojT);
    gemm_qkv<<<256, 512, 0, stream>>>(xb, WqkvT, b_qkv, QKVb, 3072, 1024);
    fenwick_attn<<<2048, 256, 0, stream>>>(QKVb, AO);
    gemm_proj<<<256, 256, 0, stream>>>(AO, WprojT, b_proj, out, 1024, 1024);
}